// Round 4
// baseline (115.327 us; speedup 1.0000x reference)
//
#include <hip/hip_runtime.h>

#define NPAIR  144
#define KLEN   512
#define GPTS   2048
#define NFRM   256
#define FPB    4                  // frames interleaved per block (float4 lanes)
#define NFG    (NFRM / FPB)       // 64 frame groups
#define GSPLIT 8                  // g splits per frame group
#define GPB    (GPTS / GSPLIT)    // 256 g per block (1 per thread)
#define NSLOT  32                 // staged lags: k in {496..511} U {0..15}
#define EPSV   1e-12f

// tau0 is geometrically bounded: |lag| <= 0.1m*16000/343 = 4.66 samples,
// so tau in {0..5} U {507..511}; slot = (tau+16)&31 maps k=496..511 -> 0..15
// and k=0..15 -> 16..31. We stage ONLY those two 64B clumps per (pair,frame).
//
// 512 blocks = 64 frame-groups x 8 g-splits, 256 threads, 2 blocks/CU
// (2 x 72 KiB LDS = 144 KiB <= 160). Sibling blocks overlap staging/gather.
__global__ __launch_bounds__(256)
void srp_gather_kernel(const float* __restrict__ x,
                       const int* __restrict__ tau0,
                       float* __restrict__ maps) {
    __shared__ __align__(16) float xc[NPAIR * NSLOT * FPB];   // 73728 B

    const int bi = blockIdx.x;
    const int fg = bi >> 3;                    // frame group
    const int gs = bi & (GSPLIT - 1);          // g split
    const int t  = threadIdx.x;
    const int g  = gs * GPB + t;

    // Stage 1152 chunks of 64 B (pair x frame x seg). 4 lanes per chunk,
    // 16 B per lane -> coalesced 64 B groups.
    const int j4 = t & 3;                      // float4 index within chunk
    #pragma unroll
    for (int k = 0; k < (NPAIR * FPB * 2) / 64; ++k) {   // 18
        int c    = (t >> 2) + k * 64;
        int pair = c >> 3;
        int fr   = (c >> 1) & 3;
        int seg  = c & 1;
        const float* src = x + ((size_t)(fg * FPB + fr) * NPAIR + pair) * KLEN
                             + (seg ? 0 : 496) + j4 * 4;
        const float4 v = *(const float4*)src;
        float* dst = &xc[(pair * NSLOT + seg * 16 + j4 * 4) * FPB + fr];
        dst[0 * FPB] = v.x;
        dst[1 * FPB] = v.y;
        dst[2 * FPB] = v.z;
        dst[3 * FPB] = v.w;
    }
    __syncthreads();

    float4 acc = {0.f, 0.f, 0.f, 0.f};
    #pragma unroll 16
    for (int j = 0; j < NPAIR; ++j) {
        int s = (tau0[(size_t)j * GPTS + g] + 16) & 31;          // coalesced
        const float4 v = *(const float4*)&xc[(j * NSLOT + s) * FPB];
        acc.x += v.x; acc.y += v.y; acc.z += v.z; acc.w += v.w;
    }

    float* mp = maps + (size_t)(fg * FPB) * GPTS + g;
    mp[0 * GPTS] = acc.x;
    mp[1 * GPTS] = acc.y;
    mp[2 * GPTS] = acc.z;
    mp[3 * GPTS] = acc.w;
}

// One block per frame: zero-mean, then divide by max.
__global__ __launch_bounds__(256)
void srp_norm_kernel(const float* __restrict__ maps, float* __restrict__ out) {
    __shared__ float red[5];
    const int f = blockIdx.x;
    const int t = threadIdx.x;
    const float4* p = (const float4*)(maps + (size_t)f * GPTS);
    float4 s0 = p[t], s1 = p[t + 256];

    const int wave = t >> 6, lane = t & 63;

    float sm = s0.x + s0.y + s0.z + s0.w + s1.x + s1.y + s1.z + s1.w;
    #pragma unroll
    for (int off = 32; off > 0; off >>= 1) sm += __shfl_down(sm, off, 64);
    if (lane == 0) red[wave] = sm;
    __syncthreads();
    if (t == 0) red[4] = (red[0] + red[1] + red[2] + red[3]) * (1.0f / (float)GPTS);
    __syncthreads();
    const float mean = red[4];

    s0.x = s0.x - mean + EPSV; s0.y = s0.y - mean + EPSV;
    s0.z = s0.z - mean + EPSV; s0.w = s0.w - mean + EPSV;
    s1.x = s1.x - mean + EPSV; s1.y = s1.y - mean + EPSV;
    s1.z = s1.z - mean + EPSV; s1.w = s1.w - mean + EPSV;

    float mx = fmaxf(fmaxf(fmaxf(s0.x, s0.y), fmaxf(s0.z, s0.w)),
                     fmaxf(fmaxf(s1.x, s1.y), fmaxf(s1.z, s1.w)));
    #pragma unroll
    for (int off = 32; off > 0; off >>= 1) mx = fmaxf(mx, __shfl_down(mx, off, 64));
    __syncthreads();
    if (lane == 0) red[wave] = mx;
    __syncthreads();
    if (t == 0) red[4] = fmaxf(fmaxf(red[0], red[1]), fmaxf(red[2], red[3]));
    __syncthreads();
    const float inv = 1.0f / red[4];

    float4* o = (float4*)(out + (size_t)f * GPTS);
    o[t]       = make_float4(s0.x * inv, s0.y * inv, s0.z * inv, s0.w * inv);
    o[t + 256] = make_float4(s1.x * inv, s1.y * inv, s1.z * inv, s1.w * inv);
}

extern "C" void kernel_launch(void* const* d_in, const int* in_sizes, int n_in,
                              void* d_out, int out_size, void* d_ws, size_t ws_size,
                              hipStream_t stream) {
    const float* x    = (const float*)d_in[0];
    const int*   tau0 = (const int*)d_in[1];
    float* out  = (float*)d_out;
    float* maps = (float*)d_ws;                  // 2 MiB intermediate

    srp_gather_kernel<<<NFG * GSPLIT, 256, 0, stream>>>(x, tau0, maps);
    srp_norm_kernel<<<NFRM, 256, 0, stream>>>(maps, out);
}